// Round 1
// baseline (522.947 us; speedup 1.0000x reference)
//
#include <hip/hip_runtime.h>
#include <hip/hip_fp16.h>

#define NN 50000
#define NE 200000
#define IND 512
#define HIDD 2000
#define LATD 128

#define M_PAD 50176    // 196*256 (256-row M-tiles for gemm1; /64 for gemm2)
#define N1_PAD 2048    // HIDD padded (pad cols forced to exact 0)
#define NBLK 196       // ceil(NN/256)

typedef _Float16 f16x8 __attribute__((ext_vector_type(8)));
typedef float f32x4 __attribute__((ext_vector_type(4)));

__device__ __forceinline__ void gload_lds16(const _Float16* g, _Float16* l) {
    __builtin_amdgcn_global_load_lds(
        (const __attribute__((address_space(1))) unsigned int*)g,
        (__attribute__((address_space(3))) unsigned int*)l,
        16, 0, 0);
}

// ---- in-degree (int): deg[col[e]] += 1 ----
__global__ void k_degree(const int* __restrict__ col, int* __restrict__ deg) {
    int e = blockIdx.x * 256 + threadIdx.x;
    if (e < NE) atomicAdd(&deg[col[e]], 1);
}

// ---- dis = rsqrt(deg + 1 self-loop) ----
__global__ void k_dis(const int* __restrict__ deg, float* __restrict__ dis) {
    int i = blockIdx.x * 256 + threadIdx.x;
    if (i < NN) dis[i] = rsqrtf((float)deg[i] + 1.0f);
}

// ---- hierarchical exclusive scan: (1) per-block sums ----
__global__ void k_bsum(const int* __restrict__ deg, int* __restrict__ bsum) {
    __shared__ int sm[4];
    int i = blockIdx.x * 256 + threadIdx.x;
    int v = (i < NN) ? deg[i] : 0;
    #pragma unroll
    for (int off = 32; off; off >>= 1) v += __shfl_down(v, off, 64);
    if ((threadIdx.x & 63) == 0) sm[threadIdx.x >> 6] = v;
    __syncthreads();
    if (threadIdx.x == 0) bsum[blockIdx.x] = sm[0] + sm[1] + sm[2] + sm[3];
}

// ---- (2) exclusive scan of the 196 block sums (one block) ----
__global__ void k_bscan(int* __restrict__ bsum) {
    __shared__ int sm[256];
    int tid = threadIdx.x;
    int v = (tid < NBLK) ? bsum[tid] : 0;
    sm[tid] = v;
    __syncthreads();
    #pragma unroll
    for (int off = 1; off < 256; off <<= 1) {
        int t = (tid >= off) ? sm[tid - off] : 0;
        __syncthreads();
        sm[tid] += t;
        __syncthreads();
    }
    if (tid < NBLK) bsum[tid] = sm[tid] - v;   // exclusive
}

// ---- (3) per-block exclusive scan + offset -> row_ptr ----
__global__ void k_scan_final(const int* __restrict__ deg, const int* __restrict__ bsum,
                             int* __restrict__ row_ptr) {
    __shared__ int sm[256];
    int b = blockIdx.x, tid = threadIdx.x;
    int i = b * 256 + tid;
    int v = (i < NN) ? deg[i] : 0;
    sm[tid] = v;
    __syncthreads();
    #pragma unroll
    for (int off = 1; off < 256; off <<= 1) {
        int t = (tid >= off) ? sm[tid - off] : 0;
        __syncthreads();
        sm[tid] += t;
        __syncthreads();
    }
    if (i < NN) row_ptr[i] = bsum[b] + sm[tid] - v;
    if (i == NN - 1) row_ptr[NN] = bsum[b] + sm[tid];
}

// ---- fill CSR: csr_src[row_ptr[c] + cursor[c]++] = r ----
__global__ void k_fill(const int* __restrict__ ei, const int* __restrict__ row_ptr,
                       int* __restrict__ cursor, int* __restrict__ csr_src) {
    int e = blockIdx.x * 256 + threadIdx.x;
    if (e < NE) {
        int r = ei[e], c = ei[NE + e];
        int pos = atomicAdd(&cursor[c], 1);
        csr_src[row_ptr[c] + pos] = r;
    }
}

// ---- LDS-tiled transpose+convert: in f32 [R][C] -> out fp16, out[c*ldo + r] ----
__global__ void k_transpose_tiled(const float* __restrict__ in,
                                  _Float16* __restrict__ out, int R, int C, int ldo) {
    __shared__ float sm[32][33];
    int c0 = blockIdx.x * 32, r0 = blockIdx.y * 32;
    int tx = threadIdx.x & 31, ty = threadIdx.x >> 5;   // 32 x 8
    #pragma unroll
    for (int i = 0; i < 4; ++i) {
        int r = r0 + ty + i * 8, c = c0 + tx;
        sm[ty + i * 8][tx] = (r < R && c < C) ? in[(size_t)r * C + c] : 0.f;
    }
    __syncthreads();
    #pragma unroll
    for (int i = 0; i < 4; ++i) {
        int c = c0 + ty + i * 8, r = r0 + tx;
        if (c < C && r < R) out[(size_t)c * ldo + r] = (_Float16)sm[tx][ty + i * 8];
    }
}

// ---- x f32 -> xh fp16 (8 elems/thread) ----
__global__ void k_xcvt(const float* __restrict__ in, _Float16* __restrict__ out, int n8) {
    int i = blockIdx.x * 256 + threadIdx.x;
    if (i < n8) {
        float4 a = ((const float4*)in)[i * 2];
        float4 b = ((const float4*)in)[i * 2 + 1];
        f16x8 o;
        o[0] = (_Float16)a.x; o[1] = (_Float16)a.y; o[2] = (_Float16)a.z; o[3] = (_Float16)a.w;
        o[4] = (_Float16)b.x; o[5] = (_Float16)b.y; o[6] = (_Float16)b.z; o[7] = (_Float16)b.w;
        ((f16x8*)out)[i] = o;
    }
}

// ---- gather-aggregate x (fp16 src): Ah[dst] = fp16(dd*(sum dis[s]*xh[s] + dd*xh[dst])) ----
__global__ void k_gather_x(const _Float16* __restrict__ xh, const int* __restrict__ row_ptr,
                           const int* __restrict__ csr_src, const float* __restrict__ dis,
                           _Float16* __restrict__ Ah) {
    int dst = blockIdx.x * 4 + (threadIdx.x >> 6);
    if (dst >= NN) return;
    int lane = threadIdx.x & 63;
    float dd = dis[dst];
    f16x8 sv = *(const f16x8*)(xh + (size_t)dst * IND + lane * 8);
    float acc[8];
    #pragma unroll
    for (int i = 0; i < 8; ++i) acc[i] = dd * (float)sv[i];
    int beg = row_ptr[dst], end = row_ptr[dst + 1];
    for (int i = beg; i < end; ++i) {
        int s = csr_src[i];
        float ns = dis[s];
        f16x8 v = *(const f16x8*)(xh + (size_t)s * IND + lane * 8);
        #pragma unroll
        for (int q = 0; q < 8; ++q) acc[q] += ns * (float)v[q];
    }
    f16x8 o;
    #pragma unroll
    for (int i = 0; i < 8; ++i) o[i] = (_Float16)(dd * acc[i]);
    *(f16x8*)(Ah + (size_t)dst * IND + lane * 8) = o;
}

// ---- gather-aggregate t + bias + sigmoid -> out (f32) ----
__global__ void k_gather_t(const float* __restrict__ t, const int* __restrict__ row_ptr,
                           const int* __restrict__ csr_src, const float* __restrict__ dis,
                           const float* __restrict__ b2, float* __restrict__ out) {
    int dst = blockIdx.x * 4 + (threadIdx.x >> 6);
    if (dst >= NN) return;
    int lane = threadIdx.x & 63;
    float dd = dis[dst];
    float2 td = *(const float2*)(t + (size_t)dst * LATD + lane * 2);
    float accx = dd * td.x, accy = dd * td.y;
    int beg = row_ptr[dst], end = row_ptr[dst + 1];
    for (int i = beg; i < end; ++i) {
        int s = csr_src[i];
        float ns = dis[s];
        float2 ts = *(const float2*)(t + (size_t)s * LATD + lane * 2);
        accx += ns * ts.x; accy += ns * ts.y;
    }
    float2 bb = *(const float2*)(b2 + lane * 2);
    float vx = dd * accx + bb.x;
    float vy = dd * accy + bb.y;
    float2 o;
    o.x = 1.0f / (1.0f + __expf(-vx));
    o.y = 1.0f / (1.0f + __expf(-vy));
    *(float2*)(out + (size_t)dst * LATD + lane * 2) = o;
}

// ============================================================================
// GEMM1: h = relu(Ah @ W1T^T + b1)
// 256x256 tile, BK=64, 8 waves (2Mx4N, per-wave 128x64 interleaved halves),
// 8-phase pipelined schedule (T3+T4 counted vmcnt(6), T2 XOR swizzle, T5 setprio).
// LDS 128 KiB: 2 bufs x {A:2 halves, B:2 halves}, half = [128][64] fp16 = 16 KB.
// Steady-state staging (1 half-tile = 2 global_load_lds per wave per phase):
//   P1:B1(t+1)  P2:A0(t+2)  P3:B0(t+2)  P4:A1(t+2)  [vmcnt(6)]
//   P5:B1(t+2)  P6:A0(t+3)  P7:B0(t+3)  P8:A1(t+3)  [vmcnt(6)]
// Each staged region is dead >=1 phase before overwrite; each vmcnt(6)+barrier
// guarantees the next K-tile fully landed (in-order vmcnt retirement).
// ============================================================================

#define AOFFB(buf, h) ((buf) * 65536 + (h) * 16384)           // smem byte offsets
#define BOFFB(buf, h) ((buf) * 65536 + 32768 + (h) * 16384)

__device__ __forceinline__ void g1_bar() {
    asm volatile("" ::: "memory");
    __builtin_amdgcn_s_barrier();
    asm volatile("" ::: "memory");
}

// stage one half-tile: global rows grow0..+127 (row stride IND), k-tile kt,
// into LDS region (byte offset). Source col pre-swizzled so that a plain
// XOR-swizzled ds_read retrieves the right bytes (both-sides rule, m173/m231).
__device__ __forceinline__ void stage_ht(const _Float16* __restrict__ g, int grow0, int kt,
                                         _Float16* smem, int region_byte, int tid) {
    const int w = tid >> 6;
    const int r = tid >> 3;                                   // 0..63 (row in 64-row chunk)
    const int sw = ((tid & 7) * 16) ^ ((r & 7) << 4);         // swizzled byte col in 128B row
    const _Float16* s0 = g + (size_t)(grow0 + r) * IND + kt * 64 + (sw >> 1);
    _Float16* d = smem + (region_byte >> 1) + w * 512;        // wave-uniform LDS base
    gload_lds16(s0, d);                                       // rows [0,64)
    gload_lds16(s0 + (size_t)64 * IND, d + 4096);             // rows [64,128)
}

#define G1_RD(off) (*(const f16x8*)(sb + (off)))
#define G1_RDA(buf, h) { _Pragma("unroll") for (int mi_ = 0; mi_ < 4; ++mi_) { \
    int rb_ = AOFFB(buf, h) + (ra + mi_ * 16) * 128; \
    a[mi_][0] = G1_RD(rb_ + ck0); a[mi_][1] = G1_RD(rb_ + ck1); } }
#define G1_RDB(buf, h, P) { _Pragma("unroll") for (int ni_ = 0; ni_ < 2; ++ni_) { \
    int rb_ = BOFFB(buf, h) + (rbb + ni_ * 16) * 128; \
    bfr[P][ni_][0] = G1_RD(rb_ + ck0); bfr[P][ni_][1] = G1_RD(rb_ + ck1); } }
#define G1_MFMA(Q, P) { __builtin_amdgcn_s_setprio(1); \
    _Pragma("unroll") for (int ks_ = 0; ks_ < 2; ++ks_) \
    _Pragma("unroll") for (int mi_ = 0; mi_ < 4; ++mi_) \
    _Pragma("unroll") for (int ni_ = 0; ni_ < 2; ++ni_) \
        acc[Q][P][mi_][ni_] = __builtin_amdgcn_mfma_f32_16x16x32_f16( \
            a[mi_][ks_], bfr[P][ni_][ks_], acc[Q][P][mi_][ni_], 0, 0, 0); \
    __builtin_amdgcn_s_setprio(0); }

template<bool LAST>
__device__ __forceinline__ void g1_iter(const _Float16* __restrict__ A,
                                        const _Float16* __restrict__ Bt,
                                        _Float16* smem, const char* sb,
                                        int t, int mBase, int nBase, int tid,
                                        int ra, int rbb, int ck0, int ck1,
                                        f32x4 (&acc)[2][2][4][2]) {
    f16x8 a[4][2], bfr[2][2][2];
    // P1: tile t (buf0), quadrant (m0,n0) -- reads A0,B0 of buf0
    G1_RDA(0, 0); G1_RDB(0, 0, 0);
    stage_ht(Bt, nBase + 128, t + 1, smem, BOFFB(1, 1), tid);
    g1_bar();
    G1_MFMA(0, 0);
    g1_bar();
    // P2: (m0,n1) -- reads B1 of buf0
    G1_RDB(0, 1, 1);
    if (!LAST) stage_ht(A, mBase, t + 2, smem, AOFFB(0, 0), tid);
    g1_bar();
    G1_MFMA(0, 1);
    g1_bar();
    // P3: (m1,n0) -- reads A1 of buf0 (B n0 kept in regs)
    G1_RDA(0, 1);
    if (!LAST) stage_ht(Bt, nBase, t + 2, smem, BOFFB(0, 0), tid);
    g1_bar();
    G1_MFMA(1, 0);
    g1_bar();
    // P4: (m1,n1) -- no new reads
    if (!LAST) stage_ht(A, mBase + 128, t + 2, smem, AOFFB(0, 1), tid);
    g1_bar();
    G1_MFMA(1, 1);
    if (LAST) { asm volatile("s_waitcnt vmcnt(0)" ::: "memory"); }
    else      { asm volatile("s_waitcnt vmcnt(6)" ::: "memory"); }
    g1_bar();
    // P5: tile t+1 (buf1), (m0,n0)
    G1_RDA(1, 0); G1_RDB(1, 0, 0);
    if (!LAST) stage_ht(Bt, nBase + 128, t + 2, smem, BOFFB(0, 1), tid);
    g1_bar();
    G1_MFMA(0, 0);
    g1_bar();
    // P6: (m0,n1)
    G1_RDB(1, 1, 1);
    if (!LAST) stage_ht(A, mBase, t + 3, smem, AOFFB(1, 0), tid);
    g1_bar();
    G1_MFMA(0, 1);
    g1_bar();
    // P7: (m1,n0)
    G1_RDA(1, 1);
    if (!LAST) stage_ht(Bt, nBase, t + 3, smem, BOFFB(1, 0), tid);
    g1_bar();
    G1_MFMA(1, 0);
    g1_bar();
    // P8: (m1,n1)
    if (!LAST) stage_ht(A, mBase + 128, t + 3, smem, AOFFB(1, 1), tid);
    g1_bar();
    G1_MFMA(1, 1);
    if (!LAST) {
        asm volatile("s_waitcnt vmcnt(6)" ::: "memory");
        g1_bar();
    }
}

__global__ __launch_bounds__(512, 2) void k_gemm1(
    const _Float16* __restrict__ A,    // [M_PAD][512]
    const _Float16* __restrict__ Bt,   // [2048][512]
    const float* __restrict__ bias,    // [2048] (pad zeros)
    _Float16* __restrict__ Ch)         // [M_PAD][2048]
{
    __shared__ __align__(16) _Float16 smem[65536];   // 128 KiB

    // XCD-bijective swizzle (1568 % 8 == 0), nT-fastest within an XCD chunk
    const int b0 = blockIdx.x;
    const int swz = (b0 & 7) * 196 + (b0 >> 3);
    const int mT = swz >> 3, nT = swz & 7;
    const int mBase = mT * 256, nBase = nT * 256;

    const int tid = threadIdx.x;
    const int lane = tid & 63;
    const int w = tid >> 6;
    const int wr = w >> 2, wc = w & 3;               // 2M x 4N wave grid
    const int lm = lane & 15, quad = lane >> 4;
    const int ra  = wr * 64 + lm;                    // A row base within a half
    const int rbb = wc * 32 + lm;                    // B row base within a half
    const int x7  = (lm & 7) << 4;
    const int ck0 = (quad * 16) ^ x7;                // swizzled byte cols, k-slice 0/1
    const int ck1 = (64 + quad * 16) ^ x7;
    const char* sb = (const char*)smem;

    f32x4 acc[2][2][4][2];
    #pragma unroll
    for (int q = 0; q < 2; ++q)
        #pragma unroll
        for (int p = 0; p < 2; ++p)
            #pragma unroll
            for (int mi = 0; mi < 4; ++mi)
                #pragma unroll
                for (int ni = 0; ni < 2; ++ni)
                    acc[q][p][mi][ni] = (f32x4){0.f, 0.f, 0.f, 0.f};

    // prologue: tile 0 complete (buf0) + tile 1 A0,B0,A1 (buf1); B1(t1) staged in first P1
    stage_ht(A,  mBase,       0, smem, AOFFB(0, 0), tid);
    stage_ht(Bt, nBase,       0, smem, BOFFB(0, 0), tid);
    stage_ht(A,  mBase + 128, 0, smem, AOFFB(0, 1), tid);
    stage_ht(Bt, nBase + 128, 0, smem, BOFFB(0, 1), tid);
    stage_ht(A,  mBase,       1, smem, AOFFB(1, 0), tid);
    stage_ht(Bt, nBase,       1, smem, BOFFB(1, 0), tid);
    stage_ht(A,  mBase + 128, 1, smem, AOFFB(1, 1), tid);
    asm volatile("s_waitcnt vmcnt(6)" ::: "memory");   // tile 0 fully landed
    g1_bar();

    #pragma unroll 1
    for (int it = 0; it < IND / 128 - 1; ++it)
        g1_iter<false>(A, Bt, smem, sb, 2 * it, mBase, nBase, tid, ra, rbb, ck0, ck1, acc);
    g1_iter<true>(A, Bt, smem, sb, IND / 64 - 2, mBase, nBase, tid, ra, rbb, ck0, ck1, acc);

    // epilogue: bias + relu + fp16 store
    #pragma unroll
    for (int q = 0; q < 2; ++q) {
        #pragma unroll
        for (int p = 0; p < 2; ++p) {
            #pragma unroll
            for (int ni = 0; ni < 2; ++ni) {
                int col = nBase + p * 128 + wc * 32 + ni * 16 + lm;
                float bv = bias[col];
                #pragma unroll
                for (int mi = 0; mi < 4; ++mi) {
                    int rowg = mBase + q * 128 + wr * 64 + mi * 16 + quad * 4;
                    f32x4 v = acc[q][p][mi][ni];
                    #pragma unroll
                    for (int r = 0; r < 4; ++r) {
                        float x = fmaxf(v[r] + bv, 0.f);
                        Ch[(size_t)(rowg + r) * N1_PAD + col] = (_Float16)x;
                    }
                }
            }
        }
    }
}

// ---- GEMM2: t = h @ W2T^T, 64x128 tile, BK=64 (2x32 slices), f32 out ----
__global__ __launch_bounds__(256, 2) void k_gemm2(
    const _Float16* __restrict__ A,    // [M_PAD][2048]
    const _Float16* __restrict__ Bt,   // [128][2048]
    float* __restrict__ Cf)            // [M_PAD][128]
{
    __shared__ __align__(16) _Float16 As[2 * 64 * 32];    //  8 KB
    __shared__ __align__(16) _Float16 Bs[2 * 128 * 32];   // 16 KB

    const int tid = threadIdx.x;
    const int lane = tid & 63;
    const int w = tid >> 6;
    const int mBase = blockIdx.x * 64;

    const int srA = w * 16 + (lane >> 2);
    const int srB = w * 32 + (lane >> 2);
    const int scol = (lane & 3) * 8;
    const _Float16* Ag  = A + (size_t)(mBase + srA) * N1_PAD + scol;
    const _Float16* Bg0 = Bt + (size_t)srB * N1_PAD + scol;
    const _Float16* Bg1 = Bg0 + (size_t)16 * N1_PAD;

    const int wm = (w & 1) * 32;
    const int wn = (w >> 1) * 64;
    const int lm = lane & 15;
    const int quad = lane >> 4;

    f32x4 acc[2][4];
    #pragma unroll
    for (int i = 0; i < 2; ++i)
        #pragma unroll
        for (int j = 0; j < 4; ++j)
            acc[i][j] = (f32x4){0.f, 0.f, 0.f, 0.f};

    for (int k0 = 0; k0 < N1_PAD; k0 += 64) {
        #pragma unroll
        for (int s = 0; s < 2; ++s) {
            gload_lds16(Ag + k0 + s * 32, As + s * 2048 + w * 512);
            gload_lds16(Bg0 + k0 + s * 32, Bs + s * 4096 + w * 1024);
            gload_lds16(Bg1 + k0 + s * 32, Bs + s * 4096 + w * 1024 + 512);
        }
        __syncthreads();

        #pragma unroll
        for (int s = 0; s < 2; ++s) {
            f16x8 af[2], bfr[4];
            #pragma unroll
            for (int mi = 0; mi < 2; ++mi)
                af[mi] = *(const f16x8*)&As[s * 2048 + (wm + mi * 16 + lm) * 32 + quad * 8];
            #pragma unroll
            for (int ni = 0; ni < 4; ++ni)
                bfr[ni] = *(const f16x8*)&Bs[s * 4096 + (wn + ni * 16 + lm) * 32 + quad * 8];
            #pragma unroll
            for (int mi = 0; mi < 2; ++mi)
                #pragma unroll
                for (int ni = 0; ni < 4; ++ni)
                    acc[mi][ni] = __builtin_amdgcn_mfma_f32_16x16x32_f16(
                        af[mi], bfr[ni], acc[mi][ni], 0, 0, 0);
        }
        __syncthreads();
    }

    #pragma unroll
    for (int mi = 0; mi < 2; ++mi) {
        #pragma unroll
        for (int ni = 0; ni < 4; ++ni) {
            int col = wn + ni * 16 + lm;
            #pragma unroll
            for (int r = 0; r < 4; ++r) {
                int rowg = mBase + wm + mi * 16 + quad * 4 + r;
                Cf[(size_t)rowg * LATD + col] = acc[mi][ni][r];
            }
        }
    }
}

extern "C" void kernel_launch(void* const* d_in, const int* in_sizes, int n_in,
                              void* d_out, int out_size, void* d_ws, size_t ws_size,
                              hipStream_t stream) {
    const float* x  = (const float*)d_in[0];
    const int* ei   = (const int*)d_in[1];
    const float* W1 = (const float*)d_in[2];
    const float* b1 = (const float*)d_in[3];
    const float* W2 = (const float*)d_in[4];
    const float* b2 = (const float*)d_in[5];
    float* out = (float*)d_out;

    char* p = (char*)d_ws;
    auto alloc = [&](size_t bytes) {
        char* q = p; p += (bytes + 255) & ~(size_t)255; return q;
    };
    int* deg        = (int*)alloc((size_t)NN * 4);
    int* bsum       = (int*)alloc((size_t)NBLK * 4);
    int* row_ptr    = (int*)alloc((size_t)(NN + 1) * 4);
    int* cursor     = (int*)alloc((size_t)NN * 4);
    int* csr_src    = (int*)alloc((size_t)NE * 4);
    float* dis      = (float*)alloc((size_t)NN * 4);
    float* b1pad    = (float*)alloc((size_t)N1_PAD * 4);
    _Float16* W1T   = (_Float16*)alloc((size_t)N1_PAD * IND * 2);   // [2048][512]
    _Float16* W2T   = (_Float16*)alloc((size_t)LATD * N1_PAD * 2);  // [128][2048]
    _Float16* xh    = (_Float16*)alloc((size_t)NN * IND * 2);
    _Float16* Ah    = (_Float16*)alloc((size_t)M_PAD * IND * 2);
    _Float16* h     = (_Float16*)alloc((size_t)M_PAD * N1_PAD * 2);
    float* t        = (float*)alloc((size_t)M_PAD * LATD * 4);

    hipMemsetAsync(deg,    0, (size_t)NN * 4, stream);
    hipMemsetAsync(cursor, 0, (size_t)NN * 4, stream);
    hipMemsetAsync(b1pad,  0, (size_t)N1_PAD * 4, stream);
    hipMemsetAsync(W1T,    0, (size_t)N1_PAD * IND * 2, stream);
    hipMemsetAsync(W2T,    0, (size_t)LATD * N1_PAD * 2, stream);
    hipMemcpyAsync(b1pad, b1, (size_t)HIDD * 4, hipMemcpyDeviceToDevice, stream);

    k_degree<<<(NE + 255) / 256, 256, 0, stream>>>(ei + NE, deg);
    k_dis<<<(NN + 255) / 256, 256, 0, stream>>>(deg, dis);
    k_bsum<<<NBLK, 256, 0, stream>>>(deg, bsum);
    k_bscan<<<1, 256, 0, stream>>>(bsum);
    k_scan_final<<<NBLK, 256, 0, stream>>>(deg, bsum, row_ptr);
    k_fill<<<(NE + 255) / 256, 256, 0, stream>>>(ei, row_ptr, cursor, csr_src);

    {
        dim3 gt1((HIDD + 31) / 32, (IND + 31) / 32);
        k_transpose_tiled<<<gt1, 256, 0, stream>>>(W1, W1T, IND, HIDD, IND);
        dim3 gt2((LATD + 31) / 32, (HIDD + 31) / 32);
        k_transpose_tiled<<<gt2, 256, 0, stream>>>(W2, W2T, HIDD, LATD, N1_PAD);
        k_xcvt<<<(NN * IND / 8 + 255) / 256, 256, 0, stream>>>(x, xh, NN * IND / 8);
    }

    k_gather_x<<<(NN + 3) / 4, 256, 0, stream>>>(xh, row_ptr, csr_src, dis, Ah);

    k_gemm1<<<(M_PAD / 256) * (N1_PAD / 256), 512, 0, stream>>>(Ah, W1T, b1pad, h);
    k_gemm2<<<M_PAD / 64, 256, 0, stream>>>(h, W2T, t);

    k_gather_t<<<(NN + 3) / 4, 256, 0, stream>>>(t, row_ptr, csr_src, dis, b2, out);
}

// Round 2
// 499.639 us; speedup vs baseline: 1.0467x; 1.0467x over previous
//
#include <hip/hip_runtime.h>
#include <hip/hip_fp16.h>

#define NN 50000
#define NE 200000
#define IND 512
#define HIDD 2000
#define LATD 128

#define M_PAD 50176    // 392*128 = 784*64
#define N1_PAD 2048    // HIDD padded (pad cols forced to exact 0)
#define MT1 392
#define SLAB1 49       // 392/8 M-tiles per XCD (exact)
#define NBLK 196       // ceil(NN/256)

typedef _Float16 f16x8 __attribute__((ext_vector_type(8)));
typedef float f32x4 __attribute__((ext_vector_type(4)));

__device__ __forceinline__ void gload_lds16(const _Float16* g, _Float16* l) {
    __builtin_amdgcn_global_load_lds(
        (const __attribute__((address_space(1))) unsigned int*)g,
        (__attribute__((address_space(3))) unsigned int*)l,
        16, 0, 0);
}

// ---- in-degree (int): deg[col[e]] += 1 ----
__global__ void k_degree(const int* __restrict__ col, int* __restrict__ deg) {
    int e = blockIdx.x * 256 + threadIdx.x;
    if (e < NE) atomicAdd(&deg[col[e]], 1);
}

// ---- dis = rsqrt(deg + 1 self-loop) ----
__global__ void k_dis(const int* __restrict__ deg, float* __restrict__ dis) {
    int i = blockIdx.x * 256 + threadIdx.x;
    if (i < NN) dis[i] = rsqrtf((float)deg[i] + 1.0f);
}

// ---- hierarchical exclusive scan: (1) per-block sums ----
__global__ void k_bsum(const int* __restrict__ deg, int* __restrict__ bsum) {
    __shared__ int sm[4];
    int i = blockIdx.x * 256 + threadIdx.x;
    int v = (i < NN) ? deg[i] : 0;
    #pragma unroll
    for (int off = 32; off; off >>= 1) v += __shfl_down(v, off, 64);
    if ((threadIdx.x & 63) == 0) sm[threadIdx.x >> 6] = v;
    __syncthreads();
    if (threadIdx.x == 0) bsum[blockIdx.x] = sm[0] + sm[1] + sm[2] + sm[3];
}

// ---- (2) exclusive scan of the 196 block sums (one block) ----
__global__ void k_bscan(int* __restrict__ bsum) {
    __shared__ int sm[256];
    int tid = threadIdx.x;
    int v = (tid < NBLK) ? bsum[tid] : 0;
    sm[tid] = v;
    __syncthreads();
    #pragma unroll
    for (int off = 1; off < 256; off <<= 1) {
        int t = (tid >= off) ? sm[tid - off] : 0;
        __syncthreads();
        sm[tid] += t;
        __syncthreads();
    }
    if (tid < NBLK) bsum[tid] = sm[tid] - v;   // exclusive
}

// ---- (3) per-block exclusive scan + offset -> row_ptr ----
__global__ void k_scan_final(const int* __restrict__ deg, const int* __restrict__ bsum,
                             int* __restrict__ row_ptr) {
    __shared__ int sm[256];
    int b = blockIdx.x, tid = threadIdx.x;
    int i = b * 256 + tid;
    int v = (i < NN) ? deg[i] : 0;
    sm[tid] = v;
    __syncthreads();
    #pragma unroll
    for (int off = 1; off < 256; off <<= 1) {
        int t = (tid >= off) ? sm[tid - off] : 0;
        __syncthreads();
        sm[tid] += t;
        __syncthreads();
    }
    if (i < NN) row_ptr[i] = bsum[b] + sm[tid] - v;
    if (i == NN - 1) row_ptr[NN] = bsum[b] + sm[tid];
}

// ---- fill CSR: csr_src[row_ptr[c] + cursor[c]++] = r ----
__global__ void k_fill(const int* __restrict__ ei, const int* __restrict__ row_ptr,
                       int* __restrict__ cursor, int* __restrict__ csr_src) {
    int e = blockIdx.x * 256 + threadIdx.x;
    if (e < NE) {
        int r = ei[e], c = ei[NE + e];
        int pos = atomicAdd(&cursor[c], 1);
        csr_src[row_ptr[c] + pos] = r;
    }
}

// ---- LDS-tiled transpose+convert: in f32 [R][C] -> out fp16, out[c*ldo + r] ----
__global__ void k_transpose_tiled(const float* __restrict__ in,
                                  _Float16* __restrict__ out, int R, int C, int ldo) {
    __shared__ float sm[32][33];
    int c0 = blockIdx.x * 32, r0 = blockIdx.y * 32;
    int tx = threadIdx.x & 31, ty = threadIdx.x >> 5;   // 32 x 8
    #pragma unroll
    for (int i = 0; i < 4; ++i) {
        int r = r0 + ty + i * 8, c = c0 + tx;
        sm[ty + i * 8][tx] = (r < R && c < C) ? in[(size_t)r * C + c] : 0.f;
    }
    __syncthreads();
    #pragma unroll
    for (int i = 0; i < 4; ++i) {
        int c = c0 + ty + i * 8, r = r0 + tx;
        if (c < C && r < R) out[(size_t)c * ldo + r] = (_Float16)sm[tx][ty + i * 8];
    }
}

// ---- x f32 -> xh fp16 (8 elems/thread) ----
__global__ void k_xcvt(const float* __restrict__ in, _Float16* __restrict__ out, int n8) {
    int i = blockIdx.x * 256 + threadIdx.x;
    if (i < n8) {
        float4 a = ((const float4*)in)[i * 2];
        float4 b = ((const float4*)in)[i * 2 + 1];
        f16x8 o;
        o[0] = (_Float16)a.x; o[1] = (_Float16)a.y; o[2] = (_Float16)a.z; o[3] = (_Float16)a.w;
        o[4] = (_Float16)b.x; o[5] = (_Float16)b.y; o[6] = (_Float16)b.z; o[7] = (_Float16)b.w;
        ((f16x8*)out)[i] = o;
    }
}

// ---- gather-aggregate x (fp16 src), latency-pipelined:
//      Ah[dst] = fp16(dd*(sum dis[s]*xh[s] + dd*xh[dst]))
//      Chunked lane-parallel index+dis prefetch (1 coalesced load each),
//      then 2-deep software pipeline on the 1 KB feature-vector gathers. ----
__global__ void k_gather_x(const _Float16* __restrict__ xh, const int* __restrict__ row_ptr,
                           const int* __restrict__ csr_src, const float* __restrict__ dis,
                           _Float16* __restrict__ Ah) {
    int dst = blockIdx.x * 4 + (threadIdx.x >> 6);
    if (dst >= NN) return;
    int lane = threadIdx.x & 63;
    float dd = dis[dst];
    const f16x8* vb = (const f16x8*)xh;                 // node stride 64 (512 halves / 8)
    f16x8 sv = vb[(size_t)dst * 64 + lane];
    float acc[8];
    #pragma unroll
    for (int q = 0; q < 8; ++q) acc[q] = dd * (float)sv[q];
    int beg = row_ptr[dst], end = row_ptr[dst + 1];
    for (int c = beg; c < end; c += 64) {
        int n = end - c; if (n > 64) n = 64;
        int li = (lane < n) ? csr_src[c + lane] : 0;    // lane-parallel idx load
        float lns = (lane < n) ? dis[li] : 0.f;         // lane-parallel dis gather
        int s0 = __shfl(li, 0);
        f16x8 vnext = vb[(size_t)s0 * 64 + lane];
        for (int j = 0; j < n; ++j) {
            f16x8 v = vnext;
            if (j + 1 < n) {
                int s1 = __shfl(li, j + 1);
                vnext = vb[(size_t)s1 * 64 + lane];     // issue next before using cur
            }
            float ns = __shfl(lns, j);
            #pragma unroll
            for (int q = 0; q < 8; ++q) acc[q] += ns * (float)v[q];
        }
    }
    f16x8 o;
    #pragma unroll
    for (int q = 0; q < 8; ++q) o[q] = (_Float16)(dd * acc[q]);
    *(f16x8*)(Ah + (size_t)dst * IND + lane * 8) = o;
}

// ---- gather-aggregate t + bias + sigmoid -> out (f32), same pipelining ----
__global__ void k_gather_t(const float* __restrict__ t, const int* __restrict__ row_ptr,
                           const int* __restrict__ csr_src, const float* __restrict__ dis,
                           const float* __restrict__ b2, float* __restrict__ out) {
    int dst = blockIdx.x * 4 + (threadIdx.x >> 6);
    if (dst >= NN) return;
    int lane = threadIdx.x & 63;
    float dd = dis[dst];
    const float2* vb = (const float2*)t;                // node stride 64 (128 f32 / 2)
    float2 td = vb[(size_t)dst * 64 + lane];
    float accx = dd * td.x, accy = dd * td.y;
    int beg = row_ptr[dst], end = row_ptr[dst + 1];
    for (int c = beg; c < end; c += 64) {
        int n = end - c; if (n > 64) n = 64;
        int li = (lane < n) ? csr_src[c + lane] : 0;
        float lns = (lane < n) ? dis[li] : 0.f;
        int s0 = __shfl(li, 0);
        float2 vnext = vb[(size_t)s0 * 64 + lane];
        for (int j = 0; j < n; ++j) {
            float2 v = vnext;
            if (j + 1 < n) {
                int s1 = __shfl(li, j + 1);
                vnext = vb[(size_t)s1 * 64 + lane];
            }
            float ns = __shfl(lns, j);
            accx += ns * v.x; accy += ns * v.y;
        }
    }
    float2 bb = *(const float2*)(b2 + lane * 2);
    float vx = dd * accx + bb.x;
    float vy = dd * accy + bb.y;
    float2 o;
    o.x = 1.0f / (1.0f + __expf(-vx));
    o.y = 1.0f / (1.0f + __expf(-vy));
    *(float2*)(out + (size_t)dst * LATD + lane * 2) = o;
}

// ---- GEMM1: h = relu(Ah @ W1T^T + b1), 128x128 tile, BK=64 (2x32 slices), XCD swizzle ----
__global__ __launch_bounds__(256, 2) void k_gemm1(
    const _Float16* __restrict__ A,    // [M_PAD][512]
    const _Float16* __restrict__ Bt,   // [2048][512]
    const float* __restrict__ bias,    // [2048] (pad zeros)
    _Float16* __restrict__ Ch)         // [M_PAD][2048]
{
    const int b = blockIdx.x;
    const int mT = (b & 7) * SLAB1 + ((b >> 3) >> 4);
    const int nT = (b >> 3) & 15;
    const int mBase = mT * 128;
    const int nBase = nT * 128;

    __shared__ __align__(16) _Float16 As[2 * 128 * 32];   // 16 KB: [slice][128][32]
    __shared__ __align__(16) _Float16 Bs[2 * 128 * 32];

    const int tid = threadIdx.x;
    const int lane = tid & 63;
    const int w = tid >> 6;

    const int srow = w * 32 + (lane >> 2);   // + (0|16) per chunk
    const int scol = (lane & 3) * 8;
    const _Float16* Ag0 = A + (size_t)(mBase + srow) * IND + scol;
    const _Float16* Ag1 = Ag0 + (size_t)16 * IND;
    const _Float16* Bg0 = Bt + (size_t)(nBase + srow) * IND + scol;
    const _Float16* Bg1 = Bg0 + (size_t)16 * IND;

    const int wm = (w >> 1) * 64;
    const int wn = (w & 1) * 64;
    const int lm = lane & 15;
    const int quad = lane >> 4;

    f32x4 acc[4][4];
    #pragma unroll
    for (int i = 0; i < 4; ++i)
        #pragma unroll
        for (int j = 0; j < 4; ++j)
            acc[i][j] = (f32x4){0.f, 0.f, 0.f, 0.f};

    for (int k0 = 0; k0 < IND; k0 += 64) {
        #pragma unroll
        for (int s = 0; s < 2; ++s) {
            gload_lds16(Ag0 + k0 + s * 32, As + s * 4096 + w * 1024);
            gload_lds16(Ag1 + k0 + s * 32, As + s * 4096 + w * 1024 + 512);
            gload_lds16(Bg0 + k0 + s * 32, Bs + s * 4096 + w * 1024);
            gload_lds16(Bg1 + k0 + s * 32, Bs + s * 4096 + w * 1024 + 512);
        }
        __syncthreads();

        #pragma unroll
        for (int s = 0; s < 2; ++s) {
            f16x8 af[4], bfr[4];
            #pragma unroll
            for (int mi = 0; mi < 4; ++mi)
                af[mi] = *(const f16x8*)&As[s * 4096 + (wm + mi * 16 + lm) * 32 + quad * 8];
            #pragma unroll
            for (int ni = 0; ni < 4; ++ni)
                bfr[ni] = *(const f16x8*)&Bs[s * 4096 + (wn + ni * 16 + lm) * 32 + quad * 8];
            #pragma unroll
            for (int mi = 0; mi < 4; ++mi)
                #pragma unroll
                for (int ni = 0; ni < 4; ++ni)
                    acc[mi][ni] = __builtin_amdgcn_mfma_f32_16x16x32_f16(
                        af[mi], bfr[ni], acc[mi][ni], 0, 0, 0);
        }
        __syncthreads();
    }

    #pragma unroll
    for (int mi = 0; mi < 4; ++mi) {
        #pragma unroll
        for (int ni = 0; ni < 4; ++ni) {
            int col = nBase + wn + ni * 16 + lm;
            float bval = bias[col];
            #pragma unroll
            for (int r = 0; r < 4; ++r) {
                int rowg = mBase + wm + mi * 16 + quad * 4 + r;
                float v = fmaxf(acc[mi][ni][r] + bval, 0.f);
                Ch[(size_t)rowg * N1_PAD + col] = (_Float16)v;
            }
        }
    }
}

// ---- GEMM2: t = h @ W2T^T, 64x128 tile, BK=64 (2x32 slices), f32 out ----
__global__ __launch_bounds__(256, 2) void k_gemm2(
    const _Float16* __restrict__ A,    // [M_PAD][2048]
    const _Float16* __restrict__ Bt,   // [128][2048]
    float* __restrict__ Cf)            // [M_PAD][128]
{
    __shared__ __align__(16) _Float16 As[2 * 64 * 32];    //  8 KB
    __shared__ __align__(16) _Float16 Bs[2 * 128 * 32];   // 16 KB

    const int tid = threadIdx.x;
    const int lane = tid & 63;
    const int w = tid >> 6;
    const int mBase = blockIdx.x * 64;

    const int srA = w * 16 + (lane >> 2);
    const int srB = w * 32 + (lane >> 2);
    const int scol = (lane & 3) * 8;
    const _Float16* Ag  = A + (size_t)(mBase + srA) * N1_PAD + scol;
    const _Float16* Bg0 = Bt + (size_t)srB * N1_PAD + scol;
    const _Float16* Bg1 = Bg0 + (size_t)16 * N1_PAD;

    const int wm = (w & 1) * 32;
    const int wn = (w >> 1) * 64;
    const int lm = lane & 15;
    const int quad = lane >> 4;

    f32x4 acc[2][4];
    #pragma unroll
    for (int i = 0; i < 2; ++i)
        #pragma unroll
        for (int j = 0; j < 4; ++j)
            acc[i][j] = (f32x4){0.f, 0.f, 0.f, 0.f};

    for (int k0 = 0; k0 < N1_PAD; k0 += 64) {
        #pragma unroll
        for (int s = 0; s < 2; ++s) {
            gload_lds16(Ag + k0 + s * 32, As + s * 2048 + w * 512);
            gload_lds16(Bg0 + k0 + s * 32, Bs + s * 4096 + w * 1024);
            gload_lds16(Bg1 + k0 + s * 32, Bs + s * 4096 + w * 1024 + 512);
        }
        __syncthreads();

        #pragma unroll
        for (int s = 0; s < 2; ++s) {
            f16x8 af[2], bfr[4];
            #pragma unroll
            for (int mi = 0; mi < 2; ++mi)
                af[mi] = *(const f16x8*)&As[s * 2048 + (wm + mi * 16 + lm) * 32 + quad * 8];
            #pragma unroll
            for (int ni = 0; ni < 4; ++ni)
                bfr[ni] = *(const f16x8*)&Bs[s * 4096 + (wn + ni * 16 + lm) * 32 + quad * 8];
            #pragma unroll
            for (int mi = 0; mi < 2; ++mi)
                #pragma unroll
                for (int ni = 0; ni < 4; ++ni)
                    acc[mi][ni] = __builtin_amdgcn_mfma_f32_16x16x32_f16(
                        af[mi], bfr[ni], acc[mi][ni], 0, 0, 0);
        }
        __syncthreads();
    }

    #pragma unroll
    for (int mi = 0; mi < 2; ++mi) {
        #pragma unroll
        for (int ni = 0; ni < 4; ++ni) {
            int col = wn + ni * 16 + lm;
            #pragma unroll
            for (int r = 0; r < 4; ++r) {
                int rowg = mBase + wm + mi * 16 + quad * 4 + r;
                Cf[(size_t)rowg * LATD + col] = acc[mi][ni][r];
            }
        }
    }
}

extern "C" void kernel_launch(void* const* d_in, const int* in_sizes, int n_in,
                              void* d_out, int out_size, void* d_ws, size_t ws_size,
                              hipStream_t stream) {
    const float* x  = (const float*)d_in[0];
    const int* ei   = (const int*)d_in[1];
    const float* W1 = (const float*)d_in[2];
    const float* b1 = (const float*)d_in[3];
    const float* W2 = (const float*)d_in[4];
    const float* b2 = (const float*)d_in[5];
    float* out = (float*)d_out;

    char* p = (char*)d_ws;
    auto alloc = [&](size_t bytes) {
        char* q = p; p += (bytes + 255) & ~(size_t)255; return q;
    };
    int* deg        = (int*)alloc((size_t)NN * 4);
    int* bsum       = (int*)alloc((size_t)NBLK * 4);
    int* row_ptr    = (int*)alloc((size_t)(NN + 1) * 4);
    int* cursor     = (int*)alloc((size_t)NN * 4);
    int* csr_src    = (int*)alloc((size_t)NE * 4);
    float* dis      = (float*)alloc((size_t)NN * 4);
    float* b1pad    = (float*)alloc((size_t)N1_PAD * 4);
    _Float16* W1T   = (_Float16*)alloc((size_t)N1_PAD * IND * 2);   // [2048][512]
    _Float16* W2T   = (_Float16*)alloc((size_t)LATD * N1_PAD * 2);  // [128][2048]
    _Float16* xh    = (_Float16*)alloc((size_t)NN * IND * 2);
    _Float16* Ah    = (_Float16*)alloc((size_t)M_PAD * IND * 2);
    _Float16* h     = (_Float16*)alloc((size_t)M_PAD * N1_PAD * 2);
    float* t        = (float*)alloc((size_t)M_PAD * LATD * 4);

    hipMemsetAsync(deg,    0, (size_t)NN * 4, stream);
    hipMemsetAsync(cursor, 0, (size_t)NN * 4, stream);
    hipMemsetAsync(b1pad,  0, (size_t)N1_PAD * 4, stream);
    hipMemsetAsync(W1T,    0, (size_t)N1_PAD * IND * 2, stream);
    hipMemsetAsync(W2T,    0, (size_t)LATD * N1_PAD * 2, stream);
    hipMemcpyAsync(b1pad, b1, (size_t)HIDD * 4, hipMemcpyDeviceToDevice, stream);

    k_degree<<<(NE + 255) / 256, 256, 0, stream>>>(ei + NE, deg);
    k_dis<<<(NN + 255) / 256, 256, 0, stream>>>(deg, dis);
    k_bsum<<<NBLK, 256, 0, stream>>>(deg, bsum);
    k_bscan<<<1, 256, 0, stream>>>(bsum);
    k_scan_final<<<NBLK, 256, 0, stream>>>(deg, bsum, row_ptr);
    k_fill<<<(NE + 255) / 256, 256, 0, stream>>>(ei, row_ptr, cursor, csr_src);

    {
        dim3 gt1((HIDD + 31) / 32, (IND + 31) / 32);
        k_transpose_tiled<<<gt1, 256, 0, stream>>>(W1, W1T, IND, HIDD, IND);
        dim3 gt2((LATD + 31) / 32, (HIDD + 31) / 32);
        k_transpose_tiled<<<gt2, 256, 0, stream>>>(W2, W2T, HIDD, LATD, N1_PAD);
        k_xcvt<<<(NN * IND / 8 + 255) / 256, 256, 0, stream>>>(x, xh, NN * IND / 8);
    }

    k_gather_x<<<(NN + 3) / 4, 256, 0, stream>>>(xh, row_ptr, csr_src, dis, Ah);

    k_gemm1<<<8 * SLAB1 * 16, 256, 0, stream>>>(Ah, W1T, b1pad, h);
    k_gemm2<<<M_PAD / 64, 256, 0, stream>>>(h, W2T, t);

    k_gather_t<<<(NN + 3) / 4, 256, 0, stream>>>(t, row_ptr, csr_src, dis, b2, out);
}